// Round 4
// baseline (497.199 us; speedup 1.0000x reference)
//
#include <hip/hip_runtime.h>

// Problem constants: X is [80,80,64] fp32; N=6400 nodes, C=64 features.
#define HH 80
#define NN 6400
#define CC 64
#define THR (1.0f / 6400.0f)   // = mean of softmax row, exactly 1/N

typedef _Float16 f16x8 __attribute__((ext_vector_type(8)));
typedef float float4v __attribute__((ext_vector_type(4)));

// ---------------------------------------------------------------------------
// prep: split X into f16 hi/lo (3-MFMA fp32-accurate matmul), row norms,
// global max norm via int-pattern atomicMax (positive floats order as ints;
// 0xAA poison is negative so no init needed), zero denom, Stab[80] table
// S(t) = sum_k exp(-(t-k)^2/2) for the analytic Ad row-normalizer.
// ---------------------------------------------------------------------------
__global__ __launch_bounds__(256) void prep_kernel(
    const float* __restrict__ X,
    _Float16* __restrict__ Xhi, _Float16* __restrict__ Xlo,
    float* __restrict__ norms, float* __restrict__ denom,
    int* __restrict__ nmax, float* __restrict__ Stab)
{
    const int id = blockIdx.x * 256 + threadIdx.x;
    const float x = X[id];
    const _Float16 h = (_Float16)x;
    const float lo = x - (float)h;
    Xhi[id] = h;
    Xlo[id] = (_Float16)lo;

    float s = x * x;
#pragma unroll
    for (int m = 1; m < 64; m <<= 1) s += __shfl_xor(s, m, 64);
    const int lane = threadIdx.x & 63;
    if (lane == 0) {
        const int row = id >> 6;           // 64 features per node == one wave
        norms[row] = s;
        atomicMax(nmax, __float_as_int(s));
    }
    if (id < NN) denom[id] = 0.f;          // ws re-poisoned every call

    const int t = (int)threadIdx.x;        // SIGNED (R2 bug: unsigned wrap)
    if (blockIdx.x == 0 && t < HH) {
        float acc = 0.f;
        for (int k = 0; k < HH; k++) {
            const float d = (float)(t - k);
            acc += __expf(-0.5f * d * d);
        }
        Stab[t] = acc;
    }
}

// ---------------------------------------------------------------------------
// pass1: denom[i] = sum_j exp(s_ij - mhat_i), mhat_i = sqrt(norms_i * nmax)
// (Cauchy-Schwarz bound on row max; mhat - truemax <= M^2/4 ~ 29 so
// denom >= e^-29, fp32-safe, no online rescale). Split-f16: s = Al*Bh +
// Ah*Bl + Ah*Bh. Wave owns 64 rows (A frags in regs, B amortized 4x).
// ---------------------------------------------------------------------------
__global__ __launch_bounds__(256) void pass1_kernel(
    const _Float16* __restrict__ Xhi, const _Float16* __restrict__ Xlo,
    const float* __restrict__ norms, const int* __restrict__ nmaxp,
    float* __restrict__ denom)
{
    const int tid = threadIdx.x;
    const int wave = tid >> 6, lane = tid & 63;
    const int q = lane >> 4, n16 = lane & 15;
    const int i0 = blockIdx.x * 256 + wave * 64;
    const int j0 = blockIdx.y * 256;
    const float nmax = __int_as_float(*nmaxp);

    f16x8 Ah[4][2], Al[4][2];
#pragma unroll
    for (int rt = 0; rt < 4; rt++) {
        const int row = i0 + rt * 16 + n16;
#pragma unroll
        for (int c = 0; c < 2; c++) {
            const int off = row * CC + c * 32 + q * 8;
            Ah[rt][c] = *(const f16x8*)(Xhi + off);
            Al[rt][c] = *(const f16x8*)(Xlo + off);
        }
    }
    float mh[4][4];
#pragma unroll
    for (int rt = 0; rt < 4; rt++)
#pragma unroll
        for (int r = 0; r < 4; r++)
            mh[rt][r] = sqrtf(norms[i0 + rt * 16 + q * 4 + r] * nmax);

    float cs[4][4];
#pragma unroll
    for (int rt = 0; rt < 4; rt++)
#pragma unroll
        for (int r = 0; r < 4; r++) cs[rt][r] = 0.f;

    for (int ct = 0; ct < 16; ct++) {
        const int col = j0 + ct * 16 + n16;
        f16x8 Bh[2], Bl[2];
#pragma unroll
        for (int c = 0; c < 2; c++) {
            const int off = col * CC + c * 32 + q * 8;
            Bh[c] = *(const f16x8*)(Xhi + off);
            Bl[c] = *(const f16x8*)(Xlo + off);
        }
#pragma unroll
        for (int rt = 0; rt < 4; rt++) {
            float4v acc = {0.f, 0.f, 0.f, 0.f};
#pragma unroll
            for (int c = 0; c < 2; c++) {
                acc = __builtin_amdgcn_mfma_f32_16x16x32_f16(Al[rt][c], Bh[c], acc, 0, 0, 0);
                acc = __builtin_amdgcn_mfma_f32_16x16x32_f16(Ah[rt][c], Bl[c], acc, 0, 0, 0);
                acc = __builtin_amdgcn_mfma_f32_16x16x32_f16(Ah[rt][c], Bh[c], acc, 0, 0, 0);
            }
#pragma unroll
            for (int r = 0; r < 4; r++)
                cs[rt][r] += __expf(acc[r] - mh[rt][r]);
        }
    }
#pragma unroll
    for (int rt = 0; rt < 4; rt++)
#pragma unroll
        for (int r = 0; r < 4; r++) {
            float v = cs[rt][r];
            v += __shfl_xor(v, 1, 64);
            v += __shfl_xor(v, 2, 64);
            v += __shfl_xor(v, 4, 64);
            v += __shfl_xor(v, 8, 64);
            if (n16 == 0)
                atomicAdd(&denom[i0 + rt * 16 + q * 4 + r], v);
        }
}

// ---------------------------------------------------------------------------
// tile_kernel: fused As + Ad over one 256x256 tile. Grid (25,25).
// Phase A (As): swapped-operand MFMA (A<-cols, B<-rows) so lane(q,n16) reg r
//   holds S[row=iw+rt*16+n16][col=jt+q*4+r] -> direct dwordx4 row stores.
// Phase B (Ad): wave w writes row it*4+w of the tile as ONE contiguous 1 KB
//   wave-store. Rows with min|ri-rj| >= 14 over the tile underflow fp32
//   (exp(-d2/2)=0 for d2>~174) -> store zeros, skip all exp/LDS (~89% of
//   pairs). Packed LDS tables kill the per-element /80 divides.
// ---------------------------------------------------------------------------
__global__ __launch_bounds__(256) void tile_kernel(
    const _Float16* __restrict__ Xhi, const _Float16* __restrict__ Xlo,
    const float* __restrict__ norms, const int* __restrict__ nmaxp,
    const float* __restrict__ denom, const float* __restrict__ Stab,
    float* __restrict__ As, float* __restrict__ Ad)
{
    __shared__ float sMh[256], sRden[256], sRec[256];
    __shared__ int sRI[256], sCJ[256];
    const int tid = threadIdx.x;
    const int i0 = blockIdx.x * 256;
    const int j0 = blockIdx.y * 256;
    {
        const int i = i0 + tid;
        const float nmax = __int_as_float(*nmaxp);
        sMh[tid] = sqrtf(norms[i] * nmax);
        sRden[tid] = 1.0f / denom[i];
        const int ri = i / HH, ci = i - ri * HH;
        sRec[tid] = 1.0f / (Stab[ri] * Stab[ci] - 1.0f);
        sRI[tid] = (ri << 8) | ci;
        const int j = j0 + tid;
        const int rj = j / HH, cj = j - rj * HH;
        sCJ[tid] = (rj << 8) | cj;
    }
    __syncthreads();

    const int wave = tid >> 6, lane = tid & 63;
    const int q = lane >> 4, n16 = lane & 15;
    const int iw = i0 + wave * 64;

    // ---------------- Phase A: As ----------------
    f16x8 Bh[4][2], Bl[4][2];
#pragma unroll
    for (int rt = 0; rt < 4; rt++) {
        const int row = iw + rt * 16 + n16;
#pragma unroll
        for (int c = 0; c < 2; c++) {
            const int off = row * CC + c * 32 + q * 8;
            Bh[rt][c] = *(const f16x8*)(Xhi + off);
            Bl[rt][c] = *(const f16x8*)(Xlo + off);
        }
    }
    float mh[4], rd[4];
#pragma unroll
    for (int rt = 0; rt < 4; rt++) {
        const int il = wave * 64 + rt * 16 + n16;
        mh[rt] = sMh[il];
        rd[rt] = sRden[il];
    }

    for (int ct = 0; ct < 16; ct++) {
        const int jt = j0 + ct * 16;
        f16x8 Ahh[2], All[2];
#pragma unroll
        for (int c = 0; c < 2; c++) {
            const int off = (jt + n16) * CC + c * 32 + q * 8;
            Ahh[c] = *(const f16x8*)(Xhi + off);
            All[c] = *(const f16x8*)(Xlo + off);
        }
        float4v acc[4];
#pragma unroll
        for (int rt = 0; rt < 4; rt++) acc[rt] = (float4v){0.f, 0.f, 0.f, 0.f};
#pragma unroll
        for (int rt = 0; rt < 4; rt++) {
#pragma unroll
            for (int c = 0; c < 2; c++) {
                acc[rt] = __builtin_amdgcn_mfma_f32_16x16x32_f16(All[c], Bh[rt][c], acc[rt], 0, 0, 0);
                acc[rt] = __builtin_amdgcn_mfma_f32_16x16x32_f16(Ahh[c], Bl[rt][c], acc[rt], 0, 0, 0);
                acc[rt] = __builtin_amdgcn_mfma_f32_16x16x32_f16(Ahh[c], Bh[rt][c], acc[rt], 0, 0, 0);
            }
        }
#pragma unroll
        for (int rt = 0; rt < 4; rt++) {
            float4v v;
#pragma unroll
            for (int r = 0; r < 4; r++) {
                const float e = __expf(acc[rt][r] - mh[rt]) * rd[rt];
                v[r] = (e < THR) ? 0.f : e;   // As < 1/N -> 0 (avg == 1/N)
            }
            *(float4v*)(As + (size_t)(iw + rt * 16 + n16) * NN + jt + q * 4) = v;
        }
    }

    // ---------------- Phase B: Ad ----------------
    const int rjlo = j0 / HH, rjhi = (j0 + 255) / HH;
    for (int it = 0; it < 64; it++) {
        const int il = it * 4 + wave;          // tile-row 0..255, wave-uniform
        const int i = i0 + il;
        const int rc = sRI[il];
        const int ri = rc >> 8, ci = rc & 255;
        const int mind = (ri < rjlo) ? (rjlo - ri) : (ri > rjhi ? ri - rjhi : 0);
        float4v v;
        if (mind >= 14) {                       // whole row of tile underflows
            v = (float4v){0.f, 0.f, 0.f, 0.f};
        } else {
            const float rec = sRec[il];
#pragma unroll
            for (int r = 0; r < 4; r++) {
                const int jl = lane * 4 + r;
                const int jc = sCJ[jl];
                const int rj = jc >> 8, cj = jc & 255;
                const int dr = ri - rj, dc = ci - cj;
                const int d2 = dr * dr + dc * dc;
                float ad = (d2 == 0 && i == j0 + jl) ? 0.f
                         : (d2 > 180) ? 0.f
                         : __expf(-0.5f * (float)d2) * rec;
                v[r] = ad;
            }
        }
        *(float4v*)(Ad + (size_t)i * NN + j0 + lane * 4) = v;
    }
}

extern "C" void kernel_launch(void* const* d_in, const int* in_sizes, int n_in,
                              void* d_out, int out_size, void* d_ws, size_t ws_size,
                              hipStream_t stream) {
    const float* X = (const float*)d_in[0];
    float* Ad = (float*)d_out;                    // output 0: [N,N]
    float* As = Ad + (size_t)NN * NN;             // output 1: [N,N]

    // workspace layout (~1.7 MB)
    char* w = (char*)d_ws;
    _Float16* Xhi = (_Float16*)(w);               // 819200 B
    _Float16* Xlo = (_Float16*)(w + 819200);      // 819200 B
    float* norms  = (float*)(w + 1638400);        // 25600 B
    float* denom  = (float*)(w + 1664000);        // 25600 B
    int*   nmax   = (int*)(w + 1689600);          // 4 B
    float* Stab   = (float*)(w + 1689664);        // 320 B (64B-aligned)

    prep_kernel<<<dim3((NN * CC) / 256), dim3(256), 0, stream>>>(
        X, Xhi, Xlo, norms, denom, nmax, Stab);
    pass1_kernel<<<dim3(25, 25), dim3(256), 0, stream>>>(
        Xhi, Xlo, norms, nmax, denom);
    tile_kernel<<<dim3(25, 25), dim3(256), 0, stream>>>(
        Xhi, Xlo, norms, nmax, denom, Stab, As, Ad);
}

// Round 5
// 455.295 us; speedup vs baseline: 1.0920x; 1.0920x over previous
//
#include <hip/hip_runtime.h>

// Problem constants: X is [80,80,64] fp32; N=6400 nodes, C=64 features.
#define HH 80
#define NN 6400
#define CC 64
#define THR (1.0f / 6400.0f)   // = mean of softmax row, exactly 1/N

typedef _Float16 f16x8 __attribute__((ext_vector_type(8)));
typedef float float4v __attribute__((ext_vector_type(4)));

// ---------------------------------------------------------------------------
// prep: split X into f16 hi/lo (3-MFMA fp32-accurate matmul), row norms,
// global max norm via int-pattern atomicMax (positive floats order as ints;
// 0xAA poison is negative so no init needed), zero denom, Stab[80] table
// S(t) = sum_k exp(-(t-k)^2/2) for the analytic Ad row-normalizer.
// ---------------------------------------------------------------------------
__global__ __launch_bounds__(256) void prep_kernel(
    const float* __restrict__ X,
    _Float16* __restrict__ Xhi, _Float16* __restrict__ Xlo,
    float* __restrict__ norms, float* __restrict__ denom,
    int* __restrict__ nmax, float* __restrict__ Stab)
{
    const int id = blockIdx.x * 256 + threadIdx.x;
    const float x = X[id];
    const _Float16 h = (_Float16)x;
    const float lo = x - (float)h;
    Xhi[id] = h;                           // cached: reused by pass1/as
    Xlo[id] = (_Float16)lo;

    float s = x * x;
#pragma unroll
    for (int m = 1; m < 64; m <<= 1) s += __shfl_xor(s, m, 64);
    const int lane = threadIdx.x & 63;
    if (lane == 0) {
        const int row = id >> 6;           // 64 features per node == one wave
        norms[row] = s;
        atomicMax(nmax, __float_as_int(s));
    }
    if (id < NN) denom[id] = 0.f;          // ws re-poisoned every call

    const int t = (int)threadIdx.x;        // SIGNED (R2 bug: unsigned wrap)
    if (blockIdx.x == 0 && t < HH) {
        float acc = 0.f;
        for (int k = 0; k < HH; k++) {
            const float d = (float)(t - k);
            acc += __expf(-0.5f * d * d);
        }
        Stab[t] = acc;
    }
}

// ---------------------------------------------------------------------------
// pass1: denom[i] = sum_j exp(s_ij - mhat_i), mhat_i = sqrt(norms_i * nmax)
// (Cauchy-Schwarz bound on row max; mhat - truemax <= M^2/4 ~ 29 so
// denom >= e^-29, fp32-safe, no online rescale). Split-f16: s = Al*Bh +
// Ah*Bl + Ah*Bh. Wave owns 64 rows (A frags in regs, B amortized 4x).
// 625 blocks, all co-resident (<= ~4 blocks/CU x 256 CU) -> no tail.
// ---------------------------------------------------------------------------
__global__ __launch_bounds__(256) void pass1_kernel(
    const _Float16* __restrict__ Xhi, const _Float16* __restrict__ Xlo,
    const float* __restrict__ norms, const int* __restrict__ nmaxp,
    float* __restrict__ denom)
{
    const int tid = threadIdx.x;
    const int wave = tid >> 6, lane = tid & 63;
    const int q = lane >> 4, n16 = lane & 15;
    const int i0 = blockIdx.x * 256 + wave * 64;
    const int j0 = blockIdx.y * 256;
    const float nmax = __int_as_float(*nmaxp);

    f16x8 Ah[4][2], Al[4][2];
#pragma unroll
    for (int rt = 0; rt < 4; rt++) {
        const int row = i0 + rt * 16 + n16;
#pragma unroll
        for (int c = 0; c < 2; c++) {
            const int off = row * CC + c * 32 + q * 8;
            Ah[rt][c] = *(const f16x8*)(Xhi + off);
            Al[rt][c] = *(const f16x8*)(Xlo + off);
        }
    }
    float mh[4][4];
#pragma unroll
    for (int rt = 0; rt < 4; rt++)
#pragma unroll
        for (int r = 0; r < 4; r++)
            mh[rt][r] = sqrtf(norms[i0 + rt * 16 + q * 4 + r] * nmax);

    float cs[4][4];
#pragma unroll
    for (int rt = 0; rt < 4; rt++)
#pragma unroll
        for (int r = 0; r < 4; r++) cs[rt][r] = 0.f;

    for (int ct = 0; ct < 16; ct++) {
        const int col = j0 + ct * 16 + n16;
        f16x8 Bh[2], Bl[2];
#pragma unroll
        for (int c = 0; c < 2; c++) {
            const int off = col * CC + c * 32 + q * 8;
            Bh[c] = *(const f16x8*)(Xhi + off);
            Bl[c] = *(const f16x8*)(Xlo + off);
        }
#pragma unroll
        for (int rt = 0; rt < 4; rt++) {
            float4v acc = {0.f, 0.f, 0.f, 0.f};
#pragma unroll
            for (int c = 0; c < 2; c++) {
                acc = __builtin_amdgcn_mfma_f32_16x16x32_f16(Al[rt][c], Bh[c], acc, 0, 0, 0);
                acc = __builtin_amdgcn_mfma_f32_16x16x32_f16(Ah[rt][c], Bl[c], acc, 0, 0, 0);
                acc = __builtin_amdgcn_mfma_f32_16x16x32_f16(Ah[rt][c], Bh[c], acc, 0, 0, 0);
            }
#pragma unroll
            for (int r = 0; r < 4; r++)
                cs[rt][r] += __expf(acc[r] - mh[rt][r]);
        }
    }
#pragma unroll
    for (int rt = 0; rt < 4; rt++)
#pragma unroll
        for (int r = 0; r < 4; r++) {
            float v = cs[rt][r];
            v += __shfl_xor(v, 1, 64);
            v += __shfl_xor(v, 2, 64);
            v += __shfl_xor(v, 4, 64);
            v += __shfl_xor(v, 8, 64);
            if (n16 == 0)
                atomicAdd(&denom[i0 + rt * 16 + q * 4 + r], v);
        }
}

// ---------------------------------------------------------------------------
// as_kernel: As = thresh(exp(s - mhat)/denom). SWAPPED MFMA operands
// (A <- cols j, B <- rows i): lane(q,n16) reg r holds D[q*4+r][n16] =
// S[row=iw+rt*16+n16][col=jt+q*4+r] -> direct dwordx4 row stores.
// R5: NONTEMPORAL stores — pure streaming output, no reuse; avoid L2
// write-allocate on the 64 B row segments. Grid (25,25), all co-resident.
// ---------------------------------------------------------------------------
__global__ __launch_bounds__(256) void as_kernel(
    const _Float16* __restrict__ Xhi, const _Float16* __restrict__ Xlo,
    const float* __restrict__ norms, const int* __restrict__ nmaxp,
    const float* __restrict__ denom, float* __restrict__ As)
{
    __shared__ float sMh[256], sRden[256];
    const int tid = threadIdx.x;
    const int i0 = blockIdx.x * 256;
    const int j0 = blockIdx.y * 256;
    {
        const int i = i0 + tid;
        const float nmax = __int_as_float(*nmaxp);
        sMh[tid] = sqrtf(norms[i] * nmax);
        sRden[tid] = 1.0f / denom[i];
    }
    __syncthreads();

    const int wave = tid >> 6, lane = tid & 63;
    const int q = lane >> 4, n16 = lane & 15;
    const int iw = i0 + wave * 64;

    f16x8 Bh[4][2], Bl[4][2];
#pragma unroll
    for (int rt = 0; rt < 4; rt++) {
        const int row = iw + rt * 16 + n16;
#pragma unroll
        for (int c = 0; c < 2; c++) {
            const int off = row * CC + c * 32 + q * 8;
            Bh[rt][c] = *(const f16x8*)(Xhi + off);
            Bl[rt][c] = *(const f16x8*)(Xlo + off);
        }
    }
    float mh[4], rd[4];
#pragma unroll
    for (int rt = 0; rt < 4; rt++) {
        const int il = wave * 64 + rt * 16 + n16;
        mh[rt] = sMh[il];
        rd[rt] = sRden[il];
    }

    for (int ct = 0; ct < 16; ct++) {
        const int jt = j0 + ct * 16;
        f16x8 Ahh[2], All[2];
#pragma unroll
        for (int c = 0; c < 2; c++) {
            const int off = (jt + n16) * CC + c * 32 + q * 8;
            Ahh[c] = *(const f16x8*)(Xhi + off);
            All[c] = *(const f16x8*)(Xlo + off);
        }
        float4v acc[4];
#pragma unroll
        for (int rt = 0; rt < 4; rt++) acc[rt] = (float4v){0.f, 0.f, 0.f, 0.f};
#pragma unroll
        for (int rt = 0; rt < 4; rt++) {
#pragma unroll
            for (int c = 0; c < 2; c++) {
                acc[rt] = __builtin_amdgcn_mfma_f32_16x16x32_f16(All[c], Bh[rt][c], acc[rt], 0, 0, 0);
                acc[rt] = __builtin_amdgcn_mfma_f32_16x16x32_f16(Ahh[c], Bl[rt][c], acc[rt], 0, 0, 0);
                acc[rt] = __builtin_amdgcn_mfma_f32_16x16x32_f16(Ahh[c], Bh[rt][c], acc[rt], 0, 0, 0);
            }
        }
#pragma unroll
        for (int rt = 0; rt < 4; rt++) {
            float4v v;
#pragma unroll
            for (int r = 0; r < 4; r++) {
                const float e = __expf(acc[rt][r] - mh[rt]) * rd[rt];
                v[r] = (e < THR) ? 0.f : e;   // As < 1/N -> 0 (avg == 1/N)
            }
            float4v* p = (float4v*)(As + (size_t)(iw + rt * 16 + n16) * NN + jt + q * 4);
            __builtin_nontemporal_store(v, p);
        }
    }
}

// ---------------------------------------------------------------------------
// ad_kernel: fully analytic Ad = exp(-d2/2) / (S(ri)S(ci) - 1), diag 0.
// Pure pattern writer: one float4 per thread, perfectly linear across the
// whole grid (R4 taught: fusing this into the tile kernel regresses).
// R5: nontemporal store.
// ---------------------------------------------------------------------------
__global__ __launch_bounds__(256) void ad_kernel(
    const float* __restrict__ Stab, float* __restrict__ Ad)
{
    const int idx = blockIdx.x * 256 + threadIdx.x;   // 10.24M groups of 4
    const int i = idx / 1600;
    const int jq = (idx - i * 1600) * 4;              // 80 % 4 == 0: one rj
    const int ri = i / HH, ci = i - ri * HH;
    const int rj = jq / HH, cj0 = jq - rj * HH;
    const float rec = 1.0f / (Stab[ri] * Stab[ci] - 1.0f);
    const int dr = ri - rj;
    const float dr2 = (float)(dr * dr);
    float4v v;
#pragma unroll
    for (int r = 0; r < 4; r++) {
        const int dc = ci - (cj0 + r);
        const float d2 = dr2 + (float)(dc * dc);
        float ad = __expf(-0.5f * d2) * rec;
        if (i == jq + r) ad = 0.f;                    // diagonal stays 0
        v[r] = ad;
    }
    __builtin_nontemporal_store(v, (float4v*)(Ad + (size_t)idx * 4));
}

extern "C" void kernel_launch(void* const* d_in, const int* in_sizes, int n_in,
                              void* d_out, int out_size, void* d_ws, size_t ws_size,
                              hipStream_t stream) {
    const float* X = (const float*)d_in[0];
    float* Ad = (float*)d_out;                    // output 0: [N,N]
    float* As = Ad + (size_t)NN * NN;             // output 1: [N,N]

    // workspace layout (~1.7 MB)
    char* w = (char*)d_ws;
    _Float16* Xhi = (_Float16*)(w);               // 819200 B
    _Float16* Xlo = (_Float16*)(w + 819200);      // 819200 B
    float* norms  = (float*)(w + 1638400);        // 25600 B
    float* denom  = (float*)(w + 1664000);        // 25600 B
    int*   nmax   = (int*)(w + 1689600);          // 4 B
    float* Stab   = (float*)(w + 1689664);        // 320 B (64B-aligned)

    prep_kernel<<<dim3((NN * CC) / 256), dim3(256), 0, stream>>>(
        X, Xhi, Xlo, norms, denom, nmax, Stab);
    pass1_kernel<<<dim3(25, 25), dim3(256), 0, stream>>>(
        Xhi, Xlo, norms, nmax, denom);
    as_kernel<<<dim3(25, 25), dim3(256), 0, stream>>>(
        Xhi, Xlo, norms, nmax, denom, As);
    ad_kernel<<<dim3(NN * NN / 4 / 256), dim3(256), 0, stream>>>(Stab, Ad);
}